// Round 3
// baseline (23464.670 us; speedup 1.0000x reference)
//
#include <hip/hip_runtime.h>

#define N_STEPS 100000
#define NDIMS 2
#define ELEMS 64              // taps*dims complex elements per step
#define LR_W 0.0625f          // 1/2^4
#define LR_F 0.0078125f       // 1/2^7
#define LR_B 0.00048828125f   // 1/2^11
#define GMAXF 30.0f
#define EPS_C 1e-8f
#define C_HALF_S10 1.58113883f    // sqrt(10)/2
#define INV_S10 0.316227766f      // 1/sqrt(10)
#define TWO_INV_S10 0.6324555320f // 2/sqrt(10)

// DPP-fused butterfly adds (VALU pipe; GCNDPPCombine folds mov_dpp+add).
// ctrl: quad_perm xor1=0xB1, xor2=0x4E; row_half_mirror=0x141 (xor4 once
// quads uniform); row_mirror=0x140 (xor8 once 8-groups uniform);
// row_bcast15=0x142 (rows 1,3); row_bcast31=0x143 (rows 2,3).
#define DPPADD(v, ctrl, rmask)                                                   \
    do {                                                                         \
        int _t = __builtin_amdgcn_update_dpp(0, __float_as_int(v), ctrl, rmask,  \
                                             0xF, true);                         \
        (v) += __int_as_float(_t);                                               \
    } while (0)

__device__ inline float allsum64(float x) {   // precompute kernel only
    x += __shfl_xor(x, 1);
    x += __shfl_xor(x, 2);
    x += __shfl_xor(x, 4);
    x += __shfl_xor(x, 8);
    x += __shfl_xor(x, 16);
    x += __shfl_xor(x, 32);
    return x;
}

// Parallel precompute: per step n
//   C[n] = {kappa, kappa*rho1.re, kappa*rho1.im, 0}
//   D[n] = {kappa*rho2.re, kappa*rho2.im}
// kappa[n] = LR_W/(sum|u_n|^2+eps), rho_k = sum conj(u_n)*u_{n+k}
__global__ __launch_bounds__(256) void ddlms_pre(const float2* __restrict__ u,
                                                 float4* __restrict__ C,
                                                 float2* __restrict__ D) {
    const int wave = threadIdx.x >> 6;
    const int lane = threadIdx.x & 63;
    const int n = blockIdx.x * 4 + wave;
    if (n >= N_STEPS) return;
    const int n1 = min(n + 1, N_STEPS - 1);
    const int n2 = min(n + 2, N_STEPS - 1);
    float2 u0 = u[(size_t)n  * ELEMS + lane];
    float2 u1 = u[(size_t)n1 * ELEMS + lane];
    float2 u2 = u[(size_t)n2 * ELEMS + lane];
    float su  = u0.x * u0.x + u0.y * u0.y;
    float r1r = u0.x * u1.x + u0.y * u1.y;   // conj(u0)*u1
    float r1i = u0.x * u1.y - u0.y * u1.x;
    float r2r = u0.x * u2.x + u0.y * u2.y;   // conj(u0)*u2
    float r2i = u0.x * u2.y - u0.y * u2.x;
    su  = allsum64(su);
    r1r = allsum64(r1r);
    r1i = allsum64(r1i);
    r2r = allsum64(r2r);
    r2i = allsum64(r2i);
    if (lane == 0) {
        float kappa = LR_W / (su + EPS_C);
        C[n] = make_float4(kappa, kappa * r1r, kappa * r1i, 0.0f);
        D[n] = make_float2(kappa * r2r, kappa * r2i);
    }
}

// Serial scan. One wave per output dim; lane l owns w element l ([taps][dims] flat).
__global__ __launch_bounds__(64, 1) void ddlms_main(const float2* __restrict__ uin,
                                                    const float4* __restrict__ C,
                                                    const float2* __restrict__ D,
                                                    float2* __restrict__ out) {
    const int dim  = blockIdx.x;    // 0 or 1
    const int lane = threadIdx.x;   // 0..63

    // per-lane w element
    float wr = 0.0f, wi = 0.0f;
    // replicated scalar state
    float vr = 0.0f, vi = 0.0f;     // v_n
    float fr = 1.0f, fi = 0.0f;     // f_n
    float br = 0.0f, bi = 0.0f;     // b_n
    float psir = 1.0f, psii = 0.0f; // conj(f_n)/|f_n|
    // off-chain derived state (functions of f_n, b_n)
    float fs2r = C_HALF_S10, fs2i = 0.0f;   // f * sqrt(10)/2
    float bs2r = 0.0f, bs2i = 0.0f;         // b * sqrt(10)/2
    float nbr = -INV_S10, nbi = -INV_S10;   // -(1/sqrt(10) + b)
    // reduction pipeline (1-iter slack): 8-group partials of w_{n-1}*u_{n+1}
    float redr = 0.0f, redi = 0.0f;
    // carry: krho2[n-1]*e_w_{n-1}
    float vpr = 0.0f, vpi = 0.0f;

    // u ring buffer: at start of iter n, ubuf[(n+k)&7] = u[n+k] for k=1..8
    float2 ubuf[8];
    float2 uc = uin[lane];          // u[0], this lane's element
#pragma unroll
    for (int k = 1; k <= 8; ++k)
        ubuf[k & 7] = uin[(size_t)k * ELEMS + lane];

    // coefficient ring, 4 steps deep (uniform-address loads)
    float4 creg[4];
    float2 dreg[4];
#pragma unroll
    for (int k = 0; k < 4; ++k) {
        creg[k] = C[k];
        dreg[k] = D[k];
    }

    float2 zbuf[8];
    float2* outp = out + dim;       // out viewed as float2[N][NDIMS]

    for (int nb = 0; nb < N_STEPS; nb += 8) {
#pragma unroll
        for (int q = 0; q < 8; ++q) {
            const int n = nb + q;

            // current-step coefficients, then prefetch step n+4 into same slot
            const float kap = creg[q & 3].x;
            const float k1r = creg[q & 3].y;
            const float k1i = creg[q & 3].z;
            const float k2r = dreg[q & 3].x;
            const float k2i = dreg[q & 3].y;
            {
                const int cn = min(n + 4, N_STEPS - 1);
                creg[q & 3] = C[cn];
                dreg[q & 3] = D[cn];
            }

            // finish reduction started last iter: P2 = sum w_{n-1}*u_{n+1}
            float P2r = redr, P2i = redi;
            DPPADD(P2r, 0x140, 0xF); DPPADD(P2i, 0x140, 0xF);  // row_mirror
            DPPADD(P2r, 0x142, 0xA); DPPADD(P2i, 0x142, 0xA);  // bcast15
            DPPADD(P2r, 0x143, 0xC); DPPADD(P2i, 0x143, 0xC);  // bcast31
            const float sP2r = __int_as_float(__builtin_amdgcn_readlane(__float_as_int(P2r), 63));
            const float sP2i = __int_as_float(__builtin_amdgcn_readlane(__float_as_int(P2i), 63));

            // start new reduction: p = w_n * u[n+2] (w not yet updated this iter)
            const float2 u2 = ubuf[(q + 2) & 7];
            float pr = fmaf(wr, u2.x, -wi * u2.y);
            float pi = fmaf(wr, u2.y,  wi * u2.x);
            DPPADD(pr, 0xB1, 0xF);  DPPADD(pi, 0xB1, 0xF);     // xor1
            DPPADD(pr, 0x4E, 0xF);  DPPADD(pi, 0x4E, 0xF);     // xor2
            DPPADD(pr, 0x141, 0xF); DPPADD(pi, 0x141, 0xF);    // half_mirror

            // u rotate + deep prefetch (8 iters ahead)
            const float2 un = ubuf[(q + 1) & 7];
            ubuf[(q + 1) & 7] = uin[(size_t)min(n + 9, N_STEPS - 1) * ELEMS + lane];

            // ---- off-chain v_n helpers ----
            const float m2v  = fmaf(vr, vr, vi * vi);
            const float me   = m2v + EPS_C;
            const float invv = __builtin_amdgcn_rcpf(me);
            const float LFi  = LR_F * invv;
            const float Gme  = GMAXF * me;

            // ---- serial chain ----
            // z = v*f + b (this step's output, pre-update state)
            const float zr = fmaf(vr, fr, fmaf(-vi, fi, br));
            const float zi = fmaf(vr, fi, fmaf( vi, fr, bi));
            zbuf[q] = make_float2(zr, zi);

            // decision in scaled domain: m = clamp(ceil(v*fs2 + bs2), -1, 2)
            // (d = (2m-1)/sqrt(10); ceil ties-to-lower matches argmin first-index)
            const float zsr = fmaf(vr, fs2r, fmaf(-vi, fs2i, bs2r));
            const float zsi = fmaf(vr, fs2i, fmaf( vi, fs2r, bs2i));
            const float mr = __builtin_amdgcn_fmed3f(ceilf(zsr), -1.0f, 2.0f);
            const float mi = __builtin_amdgcn_fmed3f(ceilf(zsi), -1.0f, 2.0f);

            // db = d - b, e = d - z  (folded: d = TWO_INV*m - INV)
            const float dbr = fmaf(TWO_INV_S10, mr, nbr);
            const float dbi = fmaf(TWO_INV_S10, mi, nbi);
            const float er  = fmaf(TWO_INV_S10, mr, -(INV_S10 + zr));
            const float ei  = fmaf(TWO_INV_S10, mi, -(INV_S10 + zi));

            // e_w = db*psi - v
            const float ewr = fmaf(dbr, psir, fmaf(-dbi, psii, -vr));
            const float ewi = fmaf(dbr, psii, fmaf( dbi, psir, -vi));

            // v_{n+1} = sP2 + vp + k1*ew
            const float baser = sP2r + vpr;
            const float basei = sP2i + vpi;
            const float vnr = fmaf(k1r, ewr, fmaf(-k1i, ewi, baser));
            const float vni = fmaf(k1r, ewi, fmaf( k1i, ewr, basei));

            // carry k2*ew for next iter
            vpr = fmaf(k2r, ewr, -k2i * ewi);
            vpi = fmaf(k2r, ewi,  k2i * ewr);

            // w += (kap*ew)*conj(u_n)  (gw clip provably inactive)
            const float mwr = kap * ewr, mwi = kap * ewi;
            wr = fmaf(mwr, uc.x, fmaf( mwi, uc.y, wr));
            wi = fmaf(mwi, uc.x, fmaf(-mwr, uc.y, wi));

            // f += (LR_F*invv*fac) * e*conj(v);  fac = min(1, G*me*rsq(e2*m2v))
            const float e2  = fmaf(er, er, ei * ei);
            const float rs  = __builtin_amdgcn_rsqf(e2 * m2v);
            const float fac = fminf(1.0f, Gme * rs);
            const float s   = LFi * fac;
            const float ecvr = fmaf(er, vr,  ei * vi);  // e*conj(v)
            const float ecvi = fmaf(ei, vr, -er * vi);
            fr = fmaf(s, ecvr, fr);
            fi = fmaf(s, ecvi, fi);

            // b += LR_B * e
            br = fmaf(LR_B, er, br);
            bi = fmaf(LR_B, ei, bi);

            // psi = conj(f)/|f|
            const float m2f = fmaf(fr, fr, fi * fi);
            const float rsf = __builtin_amdgcn_rsqf(m2f);
            psir = fr * rsf;
            psii = -fi * rsf;

            // off-chain derived state for next step
            fs2r = C_HALF_S10 * fr; fs2i = C_HALF_S10 * fi;
            bs2r = C_HALF_S10 * br; bs2i = C_HALF_S10 * bi;
            nbr = -(INV_S10 + br);  nbi = -(INV_S10 + bi);

            // rotate
            vr = vnr; vi = vni;
            uc = un;
            redr = pr; redi = pi;
        }

        // batched output store (z is replicated in every lane; one lane writes)
        if (lane == 0) {
#pragma unroll
            for (int q = 0; q < 8; ++q)
                outp[(size_t)(nb + q) * NDIMS] = zbuf[q];
        }
    }
}

extern "C" void kernel_launch(void* const* d_in, const int* in_sizes, int n_in,
                              void* d_out, int out_size, void* d_ws, size_t ws_size,
                              hipStream_t stream) {
    const float2* u = (const float2*)d_in[0];
    float4* C = (float4*)d_ws;                                             // 1.6 MB
    float2* D = (float2*)((char*)d_ws + (size_t)N_STEPS * sizeof(float4)); // +0.8 MB
    ddlms_pre<<<(N_STEPS + 3) / 4, 256, 0, stream>>>(u, C, D);
    ddlms_main<<<NDIMS, 64, 0, stream>>>(u, C, D, (float2*)d_out);
}

// Round 4
// 21689.261 us; speedup vs baseline: 1.0819x; 1.0819x over previous
//
#include <hip/hip_runtime.h>

#define N_STEPS 100000
#define NDIMS 2
#define ELEMS 64              // taps*dims complex elements per step
#define LR_W 0.0625f          // 1/2^4
#define LR_F 0.0078125f       // 1/2^7
#define LR_B 0.00048828125f   // 1/2^11
#define GMAXF 30.0f
#define EPS_C 1e-8f
#define C_HALF_S10 1.58113883f    // sqrt(10)/2
#define INV_S10 0.316227766f      // 1/sqrt(10)
#define TWO_INV_S10 0.6324555320f // 2/sqrt(10)

// DPP-fused butterfly adds (VALU pipe). ctrl: quad_perm xor1=0xB1, xor2=0x4E;
// row_half_mirror=0x141 (xor4 once quads uniform); row_mirror=0x140 (xor8 once
// 8-groups uniform); row_bcast15=0x142 (rows 1,3); row_bcast31=0x143 (rows 2,3).
#define DPPADD(v, ctrl, rmask)                                                   \
    do {                                                                         \
        int _t = __builtin_amdgcn_update_dpp(0, __float_as_int(v), ctrl, rmask,  \
                                             0xF, true);                         \
        (v) += __int_as_float(_t);                                               \
    } while (0)

__device__ inline float allsum64(float x) {   // precompute kernel only
    x += __shfl_xor(x, 1);
    x += __shfl_xor(x, 2);
    x += __shfl_xor(x, 4);
    x += __shfl_xor(x, 8);
    x += __shfl_xor(x, 16);
    x += __shfl_xor(x, 32);
    return x;
}

// Parallel precompute, packed 32B/step:
//   K[2n]   = {kappa, kappa*rho1.re, kappa*rho1.im, 0}
//   K[2n+1] = {kappa*rho2.re, kappa*rho2.im, 0, 0}
// kappa[n] = LR_W/(sum|u_n|^2+eps), rho_k = sum conj(u_n)*u_{n+k}
__global__ __launch_bounds__(256) void ddlms_pre(const float2* __restrict__ u,
                                                 float4* __restrict__ K) {
    const int wave = threadIdx.x >> 6;
    const int lane = threadIdx.x & 63;
    const int n = blockIdx.x * 4 + wave;
    if (n >= N_STEPS) return;
    const int n1 = min(n + 1, N_STEPS - 1);
    const int n2 = min(n + 2, N_STEPS - 1);
    float2 u0 = u[(size_t)n  * ELEMS + lane];
    float2 u1 = u[(size_t)n1 * ELEMS + lane];
    float2 u2 = u[(size_t)n2 * ELEMS + lane];
    float su  = u0.x * u0.x + u0.y * u0.y;
    float r1r = u0.x * u1.x + u0.y * u1.y;   // conj(u0)*u1
    float r1i = u0.x * u1.y - u0.y * u1.x;
    float r2r = u0.x * u2.x + u0.y * u2.y;   // conj(u0)*u2
    float r2i = u0.x * u2.y - u0.y * u2.x;
    su  = allsum64(su);
    r1r = allsum64(r1r);
    r1i = allsum64(r1i);
    r2r = allsum64(r2r);
    r2i = allsum64(r2i);
    if (lane == 0) {
        float kappa = LR_W / (su + EPS_C);
        K[2 * n]     = make_float4(kappa, kappa * r1r, kappa * r1i, 0.0f);
        K[2 * n + 1] = make_float4(kappa * r2r, kappa * r2i, 0.0f, 0.0f);
    }
}

// Serial scan. One wave per output dim; lane l owns w element l ([taps][dims] flat).
__global__ __launch_bounds__(64) void ddlms_main(const float2* __restrict__ uin,
                                                 const float4* __restrict__ K,
                                                 float2* __restrict__ out) {
    const int dim  = blockIdx.x;    // 0 or 1
    const int lane = threadIdx.x;   // 0..63

    // Opaque zero in a VGPR: (int)(finite * 0.0f) == 0, but the compiler cannot
    // fold it (no fast-math), so coefficient addresses stay divergent ->
    // global_load (vmcnt, in-order, precisely counted) instead of s_load
    // (lgkmcnt(0) waits for the NEWEST SMEM -> full latency exposed per step).
    const int ozero = (int)(uin[lane].x * 0.0f);
    const char* Kc = (const char*)K;
    const int koff = 32 * ozero;    // VGPR-resident 0

    // per-lane w element
    float wr = 0.0f, wi = 0.0f;
    // replicated scalar state
    float vr = 0.0f, vi = 0.0f;     // v_n
    float fr = 1.0f, fi = 0.0f;     // f_n
    float br = 0.0f, bi = 0.0f;     // b_n
    float psir = 1.0f, psii = 0.0f; // conj(f_n)/|f_n|
    // off-chain derived state (functions of f_n, b_n)
    float fs2r = C_HALF_S10, fs2i = 0.0f;   // f * sqrt(10)/2
    float bs2r = 0.0f, bs2i = 0.0f;         // b * sqrt(10)/2
    float nbr = -INV_S10, nbi = -INV_S10;   // -(1/sqrt(10) + b)
    // fully-reduced lookahead product from last iter: sP = sum w_{n-1}*u_{n+1}
    float sPr = 0.0f, sPi = 0.0f;
    // carry: krho2[n-1]*e_w_{n-1}
    float vpr = 0.0f, vpi = 0.0f;

    // u ring buffer: at start of iter n, ubuf[(n+k)&7] = u[n+k] for k=1..8
    float2 ubuf[8];
    float2 uc = uin[lane];          // u[0], this lane's element
#pragma unroll
    for (int k = 1; k <= 8; ++k)
        ubuf[k & 7] = uin[(size_t)k * ELEMS + lane];

    // coefficient ring: slot k holds step nb+k's {kap,k1} and {k2}; depth 8
    float4 kr1[8];
    float2 kr2[8];
#pragma unroll
    for (int k = 0; k < 8; ++k) {
        kr1[k] = *(const float4*)(Kc + 32 * k + koff);
        kr2[k] = *(const float2*)(Kc + 32 * k + 16 + koff);
    }

    float2 zbuf[8];
    float2* outp = out + dim;       // out viewed as float2[N][NDIMS]

    for (int nb = 0; nb < N_STEPS; nb += 8) {
#pragma unroll
        for (int q = 0; q < 8; ++q) {
            const int n = nb + q;

            // this step's coefficients (loaded 8 iters ago), then prefetch n+8
            const float kap = kr1[q].x;
            const float k1r = kr1[q].y;
            const float k1i = kr1[q].z;
            const float k2r = kr2[q].x;
            const float k2i = kr2[q].y;
            {
                const int cn = min(n + 8, N_STEPS - 1);
                kr1[q] = *(const float4*)(Kc + 32 * cn + koff);
                kr2[q] = *(const float2*)(Kc + 32 * cn + 16 + koff);
            }

            // lookahead reduction, started AND finished this iter (consumed next):
            // p = w_n * u[n+2]  (w_n = pre-update w), full 64-lane butterfly.
            // Off the serial chain — overlaps with the decision/update math.
            const float2 u2 = ubuf[(q + 2) & 7];
            float pr = fmaf(wr, u2.x, -wi * u2.y);
            float pi = fmaf(wr, u2.y,  wi * u2.x);
            DPPADD(pr, 0xB1, 0xF);  DPPADD(pi, 0xB1, 0xF);     // xor1
            DPPADD(pr, 0x4E, 0xF);  DPPADD(pi, 0x4E, 0xF);     // xor2
            DPPADD(pr, 0x141, 0xF); DPPADD(pi, 0x141, 0xF);    // xor4
            DPPADD(pr, 0x140, 0xF); DPPADD(pi, 0x140, 0xF);    // xor8
            DPPADD(pr, 0x142, 0xA); DPPADD(pi, 0x142, 0xA);    // bcast15
            DPPADD(pr, 0x143, 0xC); DPPADD(pi, 0x143, 0xC);    // bcast31
            const float sPnr = __int_as_float(__builtin_amdgcn_readlane(__float_as_int(pr), 63));
            const float sPni = __int_as_float(__builtin_amdgcn_readlane(__float_as_int(pi), 63));

            // u rotate + deep prefetch (consumed 7 iters later)
            const float2 un = ubuf[(q + 1) & 7];
            ubuf[(q + 1) & 7] = uin[(size_t)min(n + 9, N_STEPS - 1) * ELEMS + lane];

            // ---- off-chain v_n helpers ----
            const float m2v  = fmaf(vr, vr, vi * vi);
            const float me   = m2v + EPS_C;
            const float invv = __builtin_amdgcn_rcpf(me);
            const float LFi  = LR_F * invv;
            const float Gme  = GMAXF * me;

            // ---- serial chain ----
            // z = v*f + b (this step's output, pre-update state)
            const float zr = fmaf(vr, fr, fmaf(-vi, fi, br));
            const float zi = fmaf(vr, fi, fmaf( vi, fr, bi));
            zbuf[q] = make_float2(zr, zi);

            // decision in scaled domain: m = clamp(ceil(v*fs2 + bs2), -1, 2)
            // (d = (2m-1)/sqrt(10); ceil ties-to-lower matches argmin first-index)
            const float zsr = fmaf(vr, fs2r, fmaf(-vi, fs2i, bs2r));
            const float zsi = fmaf(vr, fs2i, fmaf( vi, fs2r, bs2i));
            const float mr = __builtin_amdgcn_fmed3f(ceilf(zsr), -1.0f, 2.0f);
            const float mi = __builtin_amdgcn_fmed3f(ceilf(zsi), -1.0f, 2.0f);

            // db = d - b, e = d - z  (folded: d = TWO_INV*m - INV)
            const float dbr = fmaf(TWO_INV_S10, mr, nbr);
            const float dbi = fmaf(TWO_INV_S10, mi, nbi);
            const float er  = fmaf(TWO_INV_S10, mr, -(INV_S10 + zr));
            const float ei  = fmaf(TWO_INV_S10, mi, -(INV_S10 + zi));

            // e_w = db*psi - v
            const float ewr = fmaf(dbr, psir, fmaf(-dbi, psii, -vr));
            const float ewi = fmaf(dbr, psii, fmaf( dbi, psir, -vi));

            // v_{n+1} = sP + vp + k1*ew
            const float baser = sPr + vpr;
            const float basei = sPi + vpi;
            const float vnr = fmaf(k1r, ewr, fmaf(-k1i, ewi, baser));
            const float vni = fmaf(k1r, ewi, fmaf( k1i, ewr, basei));

            // carry k2*ew for next iter
            vpr = fmaf(k2r, ewr, -k2i * ewi);
            vpi = fmaf(k2r, ewi,  k2i * ewr);

            // w += (kap*ew)*conj(u_n)  (gw clip provably inactive: 240x margin)
            const float mwr = kap * ewr, mwi = kap * ewi;
            wr = fmaf(mwr, uc.x, fmaf( mwi, uc.y, wr));
            wi = fmaf(mwi, uc.x, fmaf(-mwr, uc.y, wi));

            // f += (LR_F*invv*fac) * e*conj(v);  fac = min(1, G*me*rsq(e2*m2v))
            const float e2  = fmaf(er, er, ei * ei);
            const float rs  = __builtin_amdgcn_rsqf(e2 * m2v);
            const float fac = fminf(1.0f, Gme * rs);
            const float s   = LFi * fac;
            const float ecvr = fmaf(er, vr,  ei * vi);  // e*conj(v)
            const float ecvi = fmaf(ei, vr, -er * vi);
            fr = fmaf(s, ecvr, fr);
            fi = fmaf(s, ecvi, fi);

            // b += LR_B * e
            br = fmaf(LR_B, er, br);
            bi = fmaf(LR_B, ei, bi);

            // psi = conj(f)/|f|
            const float m2f = fmaf(fr, fr, fi * fi);
            const float rsf = __builtin_amdgcn_rsqf(m2f);
            psir = fr * rsf;
            psii = -fi * rsf;

            // off-chain derived state for next step
            fs2r = C_HALF_S10 * fr; fs2i = C_HALF_S10 * fi;
            bs2r = C_HALF_S10 * br; bs2i = C_HALF_S10 * bi;
            nbr = -(INV_S10 + br);  nbi = -(INV_S10 + bi);

            // rotate
            vr = vnr; vi = vni;
            sPr = sPnr; sPi = sPni;
            uc = un;
        }

        // batched output store (z replicated in every lane; lane 0 writes)
        if (lane == 0) {
#pragma unroll
            for (int q = 0; q < 8; ++q)
                outp[(size_t)(nb + q) * NDIMS] = zbuf[q];
        }
    }
}

extern "C" void kernel_launch(void* const* d_in, const int* in_sizes, int n_in,
                              void* d_out, int out_size, void* d_ws, size_t ws_size,
                              hipStream_t stream) {
    const float2* u = (const float2*)d_in[0];
    float4* K = (float4*)d_ws;     // 3.2 MB packed coefficients
    ddlms_pre<<<(N_STEPS + 3) / 4, 256, 0, stream>>>(u, K);
    ddlms_main<<<NDIMS, 64, 0, stream>>>(u, K, (float2*)d_out);
}

// Round 5
// 21663.002 us; speedup vs baseline: 1.0832x; 1.0012x over previous
//
#include <hip/hip_runtime.h>

#define N_STEPS 100000
#define NDIMS 2
#define ELEMS 64              // taps*dims complex elements per step
#define LR_W 0.0625f          // 1/2^4
#define LR_F 0.0078125f       // 1/2^7
#define LR_B 0.00048828125f   // 1/2^11
#define GMAXF 30.0f
#define EPS_C 1e-8f
#define C_HALF_S10 1.58113883f    // sqrt(10)/2
#define INV_S10 0.316227766f      // 1/sqrt(10)
#define TWO_INV_S10 0.6324555320f // 2/sqrt(10)

// DPP-fused butterfly adds (VALU pipe). ctrl: quad_perm xor1=0xB1, xor2=0x4E;
// row_half_mirror=0x141 (xor4 once quads uniform); row_mirror=0x140 (xor8 once
// 8-groups uniform); row_bcast15=0x142 (rows 1,3); row_bcast31=0x143 (rows 2,3).
#define DPPADD(v, ctrl, rmask)                                                   \
    do {                                                                         \
        int _t = __builtin_amdgcn_update_dpp(0, __float_as_int(v), ctrl, rmask,  \
                                             0xF, true);                         \
        (v) += __int_as_float(_t);                                               \
    } while (0)

__device__ inline float allsum64(float x) {   // precompute kernel only
    x += __shfl_xor(x, 1);
    x += __shfl_xor(x, 2);
    x += __shfl_xor(x, 4);
    x += __shfl_xor(x, 8);
    x += __shfl_xor(x, 16);
    x += __shfl_xor(x, 32);
    return x;
}

// Parallel precompute, packed 32B/step:
//   K[2n]   = {kappa, kappa*rho1.re, kappa*rho1.im, 0}
//   K[2n+1] = {kappa*rho2.re, kappa*rho2.im, 0, 0}
// kappa[n] = LR_W/(sum|u_n|^2+eps), rho_k = sum conj(u_n)*u_{n+k}
__global__ __launch_bounds__(256) void ddlms_pre(const float2* __restrict__ u,
                                                 float4* __restrict__ K) {
    const int wave = threadIdx.x >> 6;
    const int lane = threadIdx.x & 63;
    const int n = blockIdx.x * 4 + wave;
    if (n >= N_STEPS) return;
    const int n1 = min(n + 1, N_STEPS - 1);
    const int n2 = min(n + 2, N_STEPS - 1);
    float2 u0 = u[(size_t)n  * ELEMS + lane];
    float2 u1 = u[(size_t)n1 * ELEMS + lane];
    float2 u2 = u[(size_t)n2 * ELEMS + lane];
    float su  = u0.x * u0.x + u0.y * u0.y;
    float r1r = u0.x * u1.x + u0.y * u1.y;   // conj(u0)*u1
    float r1i = u0.x * u1.y - u0.y * u1.x;
    float r2r = u0.x * u2.x + u0.y * u2.y;   // conj(u0)*u2
    float r2i = u0.x * u2.y - u0.y * u2.x;
    su  = allsum64(su);
    r1r = allsum64(r1r);
    r1i = allsum64(r1i);
    r2r = allsum64(r2r);
    r2i = allsum64(r2i);
    if (lane == 0) {
        float kappa = LR_W / (su + EPS_C);
        K[2 * n]     = make_float4(kappa, kappa * r1r, kappa * r1i, 0.0f);
        K[2 * n + 1] = make_float4(kappa * r2r, kappa * r2i, 0.0f, 0.0f);
    }
}

// Serial scan. One wave per output dim; lane l owns w element l ([taps][dims] flat).
// __launch_bounds__(64, 1): 1 wave/SIMD -> ~512-VGPR budget. This is THE change
// vs round 4: allows the 8-deep prefetch rings to live in registers instead of
// being sunk to just-before-consume (R4: VGPR=72 proved the rings were dead and
// ~300 cyc/step of L2 latency was exposed on every iteration).
__global__ __launch_bounds__(64, 1) void ddlms_main(const float2* __restrict__ uin,
                                                    const float4* __restrict__ K,
                                                    float2* __restrict__ out) {
    const int dim  = blockIdx.x;    // 0 or 1
    const int lane = threadIdx.x;   // 0..63

    // Opaque zero in a VGPR: (int)(finite * 0.0f) == 0, but the compiler cannot
    // fold it, so coefficient addresses stay divergent -> global_load (vmcnt,
    // in-order, precisely counted) instead of s_load (out-of-order SMEM ->
    // lgkmcnt(0) waits on the NEWEST in-flight load = full latency per step).
    const int ozero = (int)(uin[lane].x * 0.0f);
    const char* Kc = (const char*)K;
    const int koff = 32 * ozero;    // VGPR-resident 0

    // per-lane w element
    float wr = 0.0f, wi = 0.0f;
    // replicated scalar state
    float vr = 0.0f, vi = 0.0f;     // v_n
    float fr = 1.0f, fi = 0.0f;     // f_n
    float br = 0.0f, bi = 0.0f;     // b_n
    float psir = 1.0f, psii = 0.0f; // conj(f_n)/|f_n|
    // off-chain derived state (functions of f_n, b_n)
    float fs2r = C_HALF_S10, fs2i = 0.0f;   // f * sqrt(10)/2
    float bs2r = 0.0f, bs2i = 0.0f;         // b * sqrt(10)/2
    float nbr = -INV_S10, nbi = -INV_S10;   // -(1/sqrt(10) + b)
    // fully-reduced lookahead product from last iter: sP = sum w_{n-1}*u_{n+1}
    float sPr = 0.0f, sPi = 0.0f;
    // carry: krho2[n-1]*e_w_{n-1}
    float vpr = 0.0f, vpi = 0.0f;

    // u ring buffer: at start of iter n, ubuf[(n+k)&7] = u[n+k] for k=1..8
    float2 ubuf[8];
    float2 uc = uin[lane];          // u[0], this lane's element
#pragma unroll
    for (int k = 1; k <= 8; ++k)
        ubuf[k & 7] = uin[(size_t)k * ELEMS + lane];

    // coefficient ring: slot k holds step nb+k's {kap,k1} and {k2}; depth 8
    float4 kr1[8];
    float2 kr2[8];
#pragma unroll
    for (int k = 0; k < 8; ++k) {
        kr1[k] = *(const float4*)(Kc + 32 * k + koff);
        kr2[k] = *(const float2*)(Kc + 32 * k + 16 + koff);
    }

    float2 zbuf[8];
    float2* outp = out + dim;       // out viewed as float2[N][NDIMS]

    for (int nb = 0; nb < N_STEPS; nb += 8) {
#pragma unroll
        for (int q = 0; q < 8; ++q) {
            const int n = nb + q;

            // this step's coefficients (loaded 8 iters ago), then prefetch n+8
            const float kap = kr1[q].x;
            const float k1r = kr1[q].y;
            const float k1i = kr1[q].z;
            const float k2r = kr2[q].x;
            const float k2i = kr2[q].y;
            {
                const int cn = min(n + 8, N_STEPS - 1);
                kr1[q] = *(const float4*)(Kc + 32 * cn + koff);
                kr2[q] = *(const float2*)(Kc + 32 * cn + 16 + koff);
            }

            // lookahead reduction, started AND finished this iter (consumed next):
            // p = w_n * u[n+2]  (w_n = pre-update w), full 64-lane butterfly.
            // Off the serial chain — overlaps with the decision/update math.
            const float2 u2 = ubuf[(q + 2) & 7];
            float pr = fmaf(wr, u2.x, -wi * u2.y);
            float pi = fmaf(wr, u2.y,  wi * u2.x);
            DPPADD(pr, 0xB1, 0xF);  DPPADD(pi, 0xB1, 0xF);     // xor1
            DPPADD(pr, 0x4E, 0xF);  DPPADD(pi, 0x4E, 0xF);     // xor2
            DPPADD(pr, 0x141, 0xF); DPPADD(pi, 0x141, 0xF);    // xor4
            DPPADD(pr, 0x140, 0xF); DPPADD(pi, 0x140, 0xF);    // xor8
            DPPADD(pr, 0x142, 0xA); DPPADD(pi, 0x142, 0xA);    // bcast15
            DPPADD(pr, 0x143, 0xC); DPPADD(pi, 0x143, 0xC);    // bcast31
            const float sPnr = __int_as_float(__builtin_amdgcn_readlane(__float_as_int(pr), 63));
            const float sPni = __int_as_float(__builtin_amdgcn_readlane(__float_as_int(pi), 63));

            // u rotate + deep prefetch (consumed 7 iters later)
            const float2 un = ubuf[(q + 1) & 7];
            ubuf[(q + 1) & 7] = uin[(size_t)min(n + 9, N_STEPS - 1) * ELEMS + lane];

            // ---- off-chain v_n helpers ----
            const float m2v  = fmaf(vr, vr, vi * vi);
            const float me   = m2v + EPS_C;
            const float invv = __builtin_amdgcn_rcpf(me);
            const float LFi  = LR_F * invv;
            const float Gme  = GMAXF * me;

            // ---- serial chain ----
            // z = v*f + b (this step's output, pre-update state)
            const float zr = fmaf(vr, fr, fmaf(-vi, fi, br));
            const float zi = fmaf(vr, fi, fmaf( vi, fr, bi));
            zbuf[q] = make_float2(zr, zi);

            // decision in scaled domain: m = clamp(ceil(v*fs2 + bs2), -1, 2)
            // (d = (2m-1)/sqrt(10); ceil ties-to-lower matches argmin first-index)
            const float zsr = fmaf(vr, fs2r, fmaf(-vi, fs2i, bs2r));
            const float zsi = fmaf(vr, fs2i, fmaf( vi, fs2r, bs2i));
            const float mr = __builtin_amdgcn_fmed3f(ceilf(zsr), -1.0f, 2.0f);
            const float mi = __builtin_amdgcn_fmed3f(ceilf(zsi), -1.0f, 2.0f);

            // db = d - b, e = d - z  (folded: d = TWO_INV*m - INV)
            const float dbr = fmaf(TWO_INV_S10, mr, nbr);
            const float dbi = fmaf(TWO_INV_S10, mi, nbi);
            const float er  = fmaf(TWO_INV_S10, mr, -(INV_S10 + zr));
            const float ei  = fmaf(TWO_INV_S10, mi, -(INV_S10 + zi));

            // e_w = db*psi - v
            const float ewr = fmaf(dbr, psir, fmaf(-dbi, psii, -vr));
            const float ewi = fmaf(dbr, psii, fmaf( dbi, psir, -vi));

            // v_{n+1} = sP + vp + k1*ew
            const float baser = sPr + vpr;
            const float basei = sPi + vpi;
            const float vnr = fmaf(k1r, ewr, fmaf(-k1i, ewi, baser));
            const float vni = fmaf(k1r, ewi, fmaf( k1i, ewr, basei));

            // carry k2*ew for next iter
            vpr = fmaf(k2r, ewr, -k2i * ewi);
            vpi = fmaf(k2r, ewi,  k2i * ewr);

            // w += (kap*ew)*conj(u_n)  (gw clip provably inactive: 240x margin)
            const float mwr = kap * ewr, mwi = kap * ewi;
            wr = fmaf(mwr, uc.x, fmaf( mwi, uc.y, wr));
            wi = fmaf(mwi, uc.x, fmaf(-mwr, uc.y, wi));

            // f += (LR_F*invv*fac) * e*conj(v);  fac = min(1, G*me*rsq(e2*m2v))
            const float e2  = fmaf(er, er, ei * ei);
            const float rs  = __builtin_amdgcn_rsqf(e2 * m2v);
            const float fac = fminf(1.0f, Gme * rs);
            const float s   = LFi * fac;
            const float ecvr = fmaf(er, vr,  ei * vi);  // e*conj(v)
            const float ecvi = fmaf(ei, vr, -er * vi);
            fr = fmaf(s, ecvr, fr);
            fi = fmaf(s, ecvi, fi);

            // b += LR_B * e
            br = fmaf(LR_B, er, br);
            bi = fmaf(LR_B, ei, bi);

            // psi = conj(f)/|f|
            const float m2f = fmaf(fr, fr, fi * fi);
            const float rsf = __builtin_amdgcn_rsqf(m2f);
            psir = fr * rsf;
            psii = -fi * rsf;

            // off-chain derived state for next step
            fs2r = C_HALF_S10 * fr; fs2i = C_HALF_S10 * fi;
            bs2r = C_HALF_S10 * br; bs2i = C_HALF_S10 * bi;
            nbr = -(INV_S10 + br);  nbi = -(INV_S10 + bi);

            // rotate
            vr = vnr; vi = vni;
            sPr = sPnr; sPi = sPni;
            uc = un;
        }

        // batched output store (z replicated in every lane; lane 0 writes)
        if (lane == 0) {
#pragma unroll
            for (int q = 0; q < 8; ++q)
                outp[(size_t)(nb + q) * NDIMS] = zbuf[q];
        }
    }
}

extern "C" void kernel_launch(void* const* d_in, const int* in_sizes, int n_in,
                              void* d_out, int out_size, void* d_ws, size_t ws_size,
                              hipStream_t stream) {
    const float2* u = (const float2*)d_in[0];
    float4* K = (float4*)d_ws;     // 3.2 MB packed coefficients
    ddlms_pre<<<(N_STEPS + 3) / 4, 256, 0, stream>>>(u, K);
    ddlms_main<<<NDIMS, 64, 0, stream>>>(u, K, (float2*)d_out);
}

// Round 6
// 21320.778 us; speedup vs baseline: 1.1006x; 1.0161x over previous
//
#include <hip/hip_runtime.h>

#define N_STEPS 100000
#define NDIMS 2
#define ELEMS 64              // taps*dims complex elements per step
#define LR_W 0.0625f          // 1/2^4
#define LR_F 0.0078125f       // 1/2^7
#define LR_B 0.00048828125f   // 1/2^11
#define GMAXF 30.0f
#define EPS_C 1e-8f
#define C_HALF_S10 1.58113883f    // sqrt(10)/2
#define INV_S10 0.316227766f      // 1/sqrt(10)
#define TWO_INV_S10 0.6324555320f // 2/sqrt(10)

// DPP-fused butterfly adds (VALU pipe). ctrl: quad_perm xor1=0xB1, xor2=0x4E;
// row_half_mirror=0x141 (xor4 once quads uniform); row_mirror=0x140 (xor8 once
// 8-groups uniform); row_bcast15=0x142 (rows 1,3); row_bcast31=0x143 (rows 2,3).
#define DPPADD(v, ctrl, rmask)                                                   \
    do {                                                                         \
        int _t = __builtin_amdgcn_update_dpp(0, __float_as_int(v), ctrl, rmask,  \
                                             0xF, true);                         \
        (v) += __int_as_float(_t);                                               \
    } while (0)

// broadcast lane sl's value to all lanes (sl = wave-uniform SGPR index)
__device__ inline float bcastf(float v, int sl) {
    return __int_as_float(__builtin_amdgcn_readlane(__float_as_int(v), sl));
}

__device__ inline float allsum64(float x) {   // precompute kernel only
    x += __shfl_xor(x, 1);
    x += __shfl_xor(x, 2);
    x += __shfl_xor(x, 4);
    x += __shfl_xor(x, 8);
    x += __shfl_xor(x, 16);
    x += __shfl_xor(x, 32);
    return x;
}

// Parallel precompute, packed 32B/step:
//   K[2n]   = {kappa, kappa*rho1.re, kappa*rho1.im, 0}
//   K[2n+1] = {kappa*rho2.re, kappa*rho2.im, 0, 0}
// kappa[n] = LR_W/(sum|u_n|^2+eps), rho_k = sum conj(u_n)*u_{n+k}
__global__ __launch_bounds__(256) void ddlms_pre(const float2* __restrict__ u,
                                                 float4* __restrict__ K) {
    const int wave = threadIdx.x >> 6;
    const int lane = threadIdx.x & 63;
    const int n = blockIdx.x * 4 + wave;
    if (n >= N_STEPS) return;
    const int n1 = min(n + 1, N_STEPS - 1);
    const int n2 = min(n + 2, N_STEPS - 1);
    float2 u0 = u[(size_t)n  * ELEMS + lane];
    float2 u1 = u[(size_t)n1 * ELEMS + lane];
    float2 u2 = u[(size_t)n2 * ELEMS + lane];
    float su  = u0.x * u0.x + u0.y * u0.y;
    float r1r = u0.x * u1.x + u0.y * u1.y;   // conj(u0)*u1
    float r1i = u0.x * u1.y - u0.y * u1.x;
    float r2r = u0.x * u2.x + u0.y * u2.y;   // conj(u0)*u2
    float r2i = u0.x * u2.y - u0.y * u2.x;
    su  = allsum64(su);
    r1r = allsum64(r1r);
    r1i = allsum64(r1i);
    r2r = allsum64(r2r);
    r2i = allsum64(r2i);
    if (lane == 0) {
        float kappa = LR_W / (su + EPS_C);
        K[2 * n]     = make_float4(kappa, kappa * r1r, kappa * r1i, 0.0f);
        K[2 * n + 1] = make_float4(kappa * r2r, kappa * r2i, 0.0f, 0.0f);
    }
}

// Serial scan. One wave per output dim; lane l owns w element l ([taps][dims] flat).
// NO __restrict__: the per-8-step out-store is a may-alias barrier that makes
// load rematerialization/sinking across it illegal -> the u prefetch ring must
// stay live in VGPRs (R4/R5: VGPR=72 proved restrict let LLVM delete the rings
// and re-load at consume, exposing ~300 cyc L2 latency per step).
__global__ __launch_bounds__(64, 1) void ddlms_main(const float2* uin,
                                                    const float4* K,
                                                    float2* out) {
    const int dim  = blockIdx.x;    // 0 or 1
    const int lane = threadIdx.x;   // 0..63

    // per-lane w element
    float wr = 0.0f, wi = 0.0f;
    // replicated scalar state
    float vr = 0.0f, vi = 0.0f;     // v_n
    float fr = 1.0f, fi = 0.0f;     // f_n
    float br = 0.0f, bi = 0.0f;     // b_n
    float psir = 1.0f, psii = 0.0f; // conj(f_n)/|f_n|
    // off-chain derived state (functions of f_n, b_n)
    float fs2r = C_HALF_S10, fs2i = 0.0f;   // f * sqrt(10)/2
    float bs2r = 0.0f, bs2i = 0.0f;         // b * sqrt(10)/2
    float nbr = -INV_S10, nbi = -INV_S10;   // -(1/sqrt(10) + b)
    // fully-reduced lookahead product from last iter: sP = sum w_{n-1}*u_{n+1}
    float sPr = 0.0f, sPi = 0.0f;
    // carry: krho2[n-1]*e_w_{n-1}
    float vpr = 0.0f, vpi = 0.0f;

    // u ring buffer: at start of iter n, ubuf[(n+k)&7] = u[n+k] for k=1..8
    float2 ubuf[8];
    float2 uc = uin[lane];          // u[0], this lane's element
#pragma unroll
    for (int k = 1; k <= 8; ++k)
        ubuf[k & 7] = uin[(size_t)k * ELEMS + lane];

    // Coefficient residency: lane j holds step (block_base + j)'s coefficients
    // in 6 VGPRs. Per-step broadcast via v_readlane (SGPR lane index n&63) —
    // ZERO per-step memory traffic, nothing for the compiler to rematerialize.
    // Double-buffered 64-step blocks; refresh = one coalesced per-lane load per
    // 64 steps, issued 128 steps ahead.
    const char* Kc = (const char*)K;
    float4 curA = *(const float4*)(Kc + 32 * lane);
    float2 curB = *(const float2*)(Kc + 32 * lane + 16);
    float4 nxtA = *(const float4*)(Kc + 32 * (64 + lane));
    float2 nxtB = *(const float2*)(Kc + 32 * (64 + lane) + 16);

    float2 zbuf[8];
    float2* outp = out + dim;       // out viewed as float2[N][NDIMS]

    // superblocks of 64 steps; last superblock (sb=99968) runs 32 garbage
    // steps past N_STEPS (clamped loads, guarded stores) — harmless.
    for (int sb = 0; sb < N_STEPS; sb += 64) {
        // issue refresh load for block sb+128 (consumed 2 superblocks later)
        const int ridx = min(sb + 128 + lane, N_STEPS - 1);
        const float4 rA = *(const float4*)(Kc + 32 * ridx);
        const float2 rB = *(const float2*)(Kc + 32 * ridx + 16);

        for (int nb = sb; nb < sb + 64; nb += 8) {
#pragma unroll
            for (int q = 0; q < 8; ++q) {
                const int n = nb + q;

                // coefficient broadcast from lane (n&63) — pure VALU
                const int sl = n & 63;
                const float kap = bcastf(curA.x, sl);
                const float k1r = bcastf(curA.y, sl);
                const float k1i = bcastf(curA.z, sl);
                const float k2r = bcastf(curB.x, sl);
                const float k2i = bcastf(curB.y, sl);

                // lookahead reduction, started AND finished this iter (consumed
                // next): p = w_n * u[n+2] (pre-update w), full 64-lane butterfly.
                // Off the serial chain — 1 full step of slack.
                const float2 u2 = ubuf[(q + 2) & 7];
                float pr = fmaf(wr, u2.x, -wi * u2.y);
                float pi = fmaf(wr, u2.y,  wi * u2.x);
                DPPADD(pr, 0xB1, 0xF);  DPPADD(pi, 0xB1, 0xF);     // xor1
                DPPADD(pr, 0x4E, 0xF);  DPPADD(pi, 0x4E, 0xF);     // xor2
                DPPADD(pr, 0x141, 0xF); DPPADD(pi, 0x141, 0xF);    // xor4
                DPPADD(pr, 0x140, 0xF); DPPADD(pi, 0x140, 0xF);    // xor8
                DPPADD(pr, 0x142, 0xA); DPPADD(pi, 0x142, 0xA);    // bcast15
                DPPADD(pr, 0x143, 0xC); DPPADD(pi, 0x143, 0xC);    // bcast31
                const float sPnr = bcastf(pr, 63);
                const float sPni = bcastf(pi, 63);

                // u rotate + deep prefetch (consumed 7-8 iters later; pinned by
                // the out-store alias barrier)
                const float2 un = ubuf[(q + 1) & 7];
                ubuf[(q + 1) & 7] = uin[(size_t)min(n + 9, N_STEPS - 1) * ELEMS + lane];

                // ---- off-chain v_n helpers ----
                const float m2v  = fmaf(vr, vr, vi * vi);
                const float me   = m2v + EPS_C;
                const float invv = __builtin_amdgcn_rcpf(me);
                const float LFi  = LR_F * invv;
                const float Gme  = GMAXF * me;

                // ---- serial chain ----
                // z = v*f + b (this step's output, pre-update state)
                const float zr = fmaf(vr, fr, fmaf(-vi, fi, br));
                const float zi = fmaf(vr, fi, fmaf( vi, fr, bi));
                zbuf[q] = make_float2(zr, zi);

                // decision in scaled domain: m = clamp(ceil(v*fs2+bs2), -1, 2)
                // (d = (2m-1)/sqrt(10); ceil ties-to-lower = argmin first-index)
                const float zsr = fmaf(vr, fs2r, fmaf(-vi, fs2i, bs2r));
                const float zsi = fmaf(vr, fs2i, fmaf( vi, fs2r, bs2i));
                const float mr = __builtin_amdgcn_fmed3f(ceilf(zsr), -1.0f, 2.0f);
                const float mi = __builtin_amdgcn_fmed3f(ceilf(zsi), -1.0f, 2.0f);

                // db = d - b, e = d - z  (folded: d = TWO_INV*m - INV)
                const float dbr = fmaf(TWO_INV_S10, mr, nbr);
                const float dbi = fmaf(TWO_INV_S10, mi, nbi);
                const float er  = fmaf(TWO_INV_S10, mr, -(INV_S10 + zr));
                const float ei  = fmaf(TWO_INV_S10, mi, -(INV_S10 + zi));

                // e_w = db*psi - v
                const float ewr = fmaf(dbr, psir, fmaf(-dbi, psii, -vr));
                const float ewi = fmaf(dbr, psii, fmaf( dbi, psir, -vi));

                // v_{n+1} = sP + vp + k1*ew
                const float baser = sPr + vpr;
                const float basei = sPi + vpi;
                const float vnr = fmaf(k1r, ewr, fmaf(-k1i, ewi, baser));
                const float vni = fmaf(k1r, ewi, fmaf( k1i, ewr, basei));

                // carry k2*ew for next iter
                vpr = fmaf(k2r, ewr, -k2i * ewi);
                vpi = fmaf(k2r, ewi,  k2i * ewr);

                // w += (kap*ew)*conj(u_n)  (gw clip provably inactive: 240x margin)
                const float mwr = kap * ewr, mwi = kap * ewi;
                wr = fmaf(mwr, uc.x, fmaf( mwi, uc.y, wr));
                wi = fmaf(mwi, uc.x, fmaf(-mwr, uc.y, wi));

                // f += (LR_F*invv*fac)*e*conj(v); fac = min(1, G*me*rsq(e2*m2v))
                const float e2  = fmaf(er, er, ei * ei);
                const float rs  = __builtin_amdgcn_rsqf(e2 * m2v);
                const float fac = fminf(1.0f, Gme * rs);
                const float s   = LFi * fac;
                const float ecvr = fmaf(er, vr,  ei * vi);  // e*conj(v)
                const float ecvi = fmaf(ei, vr, -er * vi);
                fr = fmaf(s, ecvr, fr);
                fi = fmaf(s, ecvi, fi);

                // b += LR_B * e
                br = fmaf(LR_B, er, br);
                bi = fmaf(LR_B, ei, bi);

                // psi = conj(f)/|f|
                const float m2f = fmaf(fr, fr, fi * fi);
                const float rsf = __builtin_amdgcn_rsqf(m2f);
                psir = fr * rsf;
                psii = -fi * rsf;

                // off-chain derived state for next step
                fs2r = C_HALF_S10 * fr; fs2i = C_HALF_S10 * fi;
                bs2r = C_HALF_S10 * br; bs2i = C_HALF_S10 * bi;
                nbr = -(INV_S10 + br);  nbi = -(INV_S10 + bi);

                // rotate
                vr = vnr; vi = vni;
                sPr = sPnr; sPi = sPni;
                uc = un;
            }

            // batched output store (z replicated in every lane; lane 0 writes).
            // nb < N_STEPS guards the tail superblock's garbage steps.
            if (lane == 0 && nb < N_STEPS) {
#pragma unroll
                for (int q = 0; q < 8; ++q)
                    outp[(size_t)(nb + q) * NDIMS] = zbuf[q];
            }
        }

        // rotate coefficient blocks
        curA = nxtA; curB = nxtB;
        nxtA = rA;   nxtB = rB;
    }
}

extern "C" void kernel_launch(void* const* d_in, const int* in_sizes, int n_in,
                              void* d_out, int out_size, void* d_ws, size_t ws_size,
                              hipStream_t stream) {
    const float2* u = (const float2*)d_in[0];
    float4* K = (float4*)d_ws;     // 3.2 MB packed coefficients
    ddlms_pre<<<(N_STEPS + 3) / 4, 256, 0, stream>>>(u, K);
    ddlms_main<<<NDIMS, 64, 0, stream>>>(u, K, (float2*)d_out);
}